// Round 4
// baseline (241.229 us; speedup 1.0000x reference)
//
#include <hip/hip_runtime.h>

// LocallyConnected3DFlipout:
//   out[b,p,f] = sum_k patch[b,p,k]*loc[p,k,f]
//              + sign_out[b,p,f]*sum_k (x*sign_in)patch[b,p,k]*(softplus(rho)*eps)[p,k,f]
//              + bias[f]
// patch k = c*27 + (kd*9+kh*3+kw)  (channel slowest, spatial row-major fastest).
//
// R4: two-kernel split.
//  K1 (pack): loc/rho/eps -> bf16-packed {mean f0..3, noise f0..3} uint4 per
//    (p,k), stored tiled w[pt][k2][pl] (pt = p/64, pl = p%64, k2 = t*4+c) in
//    d_ws. LDS-transposed so reads AND writes are coalesced. Pure streaming,
//    114 MB R + 38 MB W.
//  K2 (main): wave = 64 consecutive p -> all loads/stores lane-stride 16 B
//    coalesced. No LDS, no barriers (R3's lockstep stage/compute phases and
//    scattered 4-segment loads were the ~50% stall). Weight tile sharing
//    across the block's 4 waves rides on L1. 88 MB traffic.
// Falls back to the R3 single kernel if ws_size < 38 MB.

constexpr int Bn   = 32;
constexpr int Dn   = 30;
constexpr int Cn   = 4;
constexpr int ODn  = 28;
constexpr int Pn   = ODn * ODn * ODn;   // 21952
constexpr int Tt   = 27;
constexpr int Kn   = Tt * Cn;           // 108
constexpr int PT   = 64;                // p-tile (one wave of p)
constexpr int NPT  = Pn / PT;           // 343
constexpr size_t WS_NEED = (size_t)Pn * Kn * 16;   // 37,933,056 B

__device__ __forceinline__ unsigned bf16rne(float f) {
    unsigned u = __float_as_uint(f);
    return (u + 0x7fffu + ((u >> 16) & 1u)) >> 16;
}
__device__ __forceinline__ float bflo(unsigned u) { return __uint_as_float(u << 16); }
__device__ __forceinline__ float bfhi(unsigned u) { return __uint_as_float(u & 0xffff0000u); }

// ---------------- K1: pack + transpose ----------------
// grid (NPT, 4): block = (p-tile pt, channel c). Source k = c*27 + t.
// Phase A: read (64 p x 27 t) float4s of loc/rho/eps, k-fastest lanes ->
//   coalesced 432 B runs; pack; write LDS [t][p] (stride 66 -> max 4-way).
// Phase B: p-fastest lanes read LDS conflict-free, write w[pt][t*4+c][pl]
//   contiguous 1 KB segments.
__global__ __launch_bounds__(256) void lc3d_pack(
    const float4* __restrict__ loc4,
    const float4* __restrict__ rho4,
    const float4* __restrict__ eps4,
    uint4* __restrict__ w)
{
    __shared__ uint4 lds[Tt * 66];
    const int pt = blockIdx.x;
    const int c  = blockIdx.y;
    const int p_base = pt * PT;
    const int tid = threadIdx.x;

    for (int g = tid; g < PT * Tt; g += 256) {
        const int t     = g % Tt;
        const int p_loc = g / Tt;
        const size_t src = (size_t)(p_base + p_loc) * Kn + c * Tt + t;
        const float4 L = loc4[src];
        const float4 R = rho4[src];
        const float4 E = eps4[src];
        float nx = (R.x > 15.f ? R.x : __logf(1.f + __expf(R.x))) * E.x;
        float ny = (R.y > 15.f ? R.y : __logf(1.f + __expf(R.y))) * E.y;
        float nz = (R.z > 15.f ? R.z : __logf(1.f + __expf(R.z))) * E.z;
        float nw = (R.w > 15.f ? R.w : __logf(1.f + __expf(R.w))) * E.w;
        uint4 pk;
        pk.x = bf16rne(L.x) | (bf16rne(L.y) << 16);
        pk.y = bf16rne(L.z) | (bf16rne(L.w) << 16);
        pk.z = bf16rne(nx)  | (bf16rne(ny) << 16);
        pk.w = bf16rne(nz)  | (bf16rne(nw) << 16);
        lds[t * 66 + p_loc] = pk;
    }
    __syncthreads();

    for (int g = tid; g < PT * Tt; g += 256) {
        const int p_loc = g & 63;
        const int t     = g >> 6;            // 0..26
        w[((size_t)pt * Kn + t * 4 + c) * PT + p_loc] = lds[t * 66 + p_loc];
    }
}

// ---------------- K2: main compute ----------------
// grid (NPT, 4): block = (p-tile, batch-group of 8). 256 threads =
// 64 pl x 4 bh; thread handles batches b0 = bg*8+bh*2 and b0+1.
__global__ __launch_bounds__(256) void lc3d_main(
    const uint4* __restrict__ w,        // [NPT][108][64] packed bf16
    const float4* __restrict__ x4,      // [B,30,30,30] voxels (float4 = 4 ch)
    const float4* __restrict__ s4,      // sign_in, same shape
    const float* __restrict__ bias,     // [4]
    const float4* __restrict__ so4,     // sign_out [B,P]
    float4* __restrict__ out4)          // [B,P]
{
    const int tid = threadIdx.x;
    const int pl  = tid & 63;
    const int bh  = tid >> 6;           // 0..3
    const int pt  = blockIdx.x;
    const int bg  = blockIdx.y;
    const int p   = pt * PT + pl;
    const int b0  = bg * 8 + bh * 2;
    const int b1  = b0 + 1;

    const int od   = p / (ODn * ODn);
    const int prem = p - od * (ODn * ODn);
    const int oh   = prem / ODn;
    const int ow   = prem - oh * ODn;

    const size_t v0 = (((size_t)b0 * Dn + od) * Dn + oh) * Dn + ow;
    const size_t v1 = (((size_t)b1 * Dn + od) * Dn + oh) * Dn + ow;
    const uint4* wp = w + (size_t)pt * (Kn * PT) + pl;

    float a00=0.f,a01=0.f,a02=0.f,a03=0.f;   // mean acc, b0
    float a10=0.f,a11=0.f,a12=0.f,a13=0.f;   // mean acc, b1
    float n00=0.f,n01=0.f,n02=0.f,n03=0.f;   // noise acc, b0
    float n10=0.f,n11=0.f,n12=0.f,n13=0.f;   // noise acc, b1

#define CHAN(WV, xa_c, sa_c, xb_c, sb_c)                                     \
    {                                                                        \
        const float m0 = bflo(WV.x), m1 = bfhi(WV.x);                        \
        const float m2 = bflo(WV.y), m3 = bfhi(WV.y);                        \
        const float q0 = bflo(WV.z), q1 = bfhi(WV.z);                        \
        const float q2 = bflo(WV.w), q3 = bfhi(WV.w);                        \
        a00 = fmaf(xa_c, m0, a00); a01 = fmaf(xa_c, m1, a01);                \
        a02 = fmaf(xa_c, m2, a02); a03 = fmaf(xa_c, m3, a03);                \
        a10 = fmaf(xb_c, m0, a10); a11 = fmaf(xb_c, m1, a11);                \
        a12 = fmaf(xb_c, m2, a12); a13 = fmaf(xb_c, m3, a13);                \
        const float ya = (xa_c) * (sa_c);                                    \
        const float yb = (xb_c) * (sb_c);                                    \
        n00 = fmaf(ya, q0, n00); n01 = fmaf(ya, q1, n01);                    \
        n02 = fmaf(ya, q2, n02); n03 = fmaf(ya, q3, n03);                    \
        n10 = fmaf(yb, q0, n10); n11 = fmaf(yb, q1, n11);                    \
        n12 = fmaf(yb, q2, n12); n13 = fmaf(yb, q3, n13);                    \
    }

    #pragma unroll
    for (int kd = 0; kd < 3; ++kd) {
        #pragma unroll
        for (int kh = 0; kh < 3; ++kh) {
            #pragma unroll
            for (int kw = 0; kw < 3; ++kw) {
                const int t    = (kd * 3 + kh) * 3 + kw;
                const int roff = (kd * Dn + kh) * Dn + kw;
                const float4 xa = x4[v0 + roff];
                const float4 sa = s4[v0 + roff];
                const float4 xb = x4[v1 + roff];
                const float4 sb = s4[v1 + roff];
                const uint4 w0 = wp[(t * 4 + 0) * PT];
                const uint4 w1 = wp[(t * 4 + 1) * PT];
                const uint4 w2 = wp[(t * 4 + 2) * PT];
                const uint4 w3 = wp[(t * 4 + 3) * PT];
                CHAN(w0, xa.x, sa.x, xb.x, sb.x);
                CHAN(w1, xa.y, sa.y, xb.y, sb.y);
                CHAN(w2, xa.z, sa.z, xb.z, sb.z);
                CHAN(w3, xa.w, sa.w, xb.w, sb.w);
            }
        }
    }
#undef CHAN

    const float4 bi = *(const float4*)bias;
    const size_t ob0 = (size_t)b0 * Pn + p;
    const size_t ob1 = (size_t)b1 * Pn + p;
    const float4 so0 = so4[ob0];
    const float4 so1 = so4[ob1];
    float4 o0, o1;
    o0.x = fmaf(so0.x, n00, a00) + bi.x;
    o0.y = fmaf(so0.y, n01, a01) + bi.y;
    o0.z = fmaf(so0.z, n02, a02) + bi.z;
    o0.w = fmaf(so0.w, n03, a03) + bi.w;
    o1.x = fmaf(so1.x, n10, a10) + bi.x;
    o1.y = fmaf(so1.y, n11, a11) + bi.y;
    o1.z = fmaf(so1.z, n12, a12) + bi.z;
    o1.w = fmaf(so1.w, n13, a13) + bi.w;
    out4[ob0] = o0;
    out4[ob1] = o1;
}

// ---------------- Fallback: R3 single kernel (used if ws too small) ----------------
constexpr int PPB = 16;
constexpr int WSTRIDE = Kn + 1;

__global__ __launch_bounds__(256) void lc3d_flipout_kernel(
    const float* __restrict__ x, const float* __restrict__ loc,
    const float* __restrict__ rho, const float* __restrict__ bias,
    const float* __restrict__ eps, const float* __restrict__ sgn_in,
    const float* __restrict__ sgn_out, float* __restrict__ out)
{
    __shared__ uint4 wsh[PPB * WSTRIDE];
    const int tid = threadIdx.x;
    const int p_base = blockIdx.x * PPB;
    const float4* loc4 = (const float4*)loc + (size_t)p_base * Kn;
    const float4* rho4 = (const float4*)rho + (size_t)p_base * Kn;
    const float4* eps4 = (const float4*)eps + (size_t)p_base * Kn;
    for (int g = tid; g < PPB * Kn; g += 256) {
        const int plc = g / Kn;
        const int k   = g - plc * Kn;
        const float4 L = loc4[g];
        const float4 R = rho4[g];
        const float4 E = eps4[g];
        float nx = (R.x > 15.f ? R.x : __logf(1.f + __expf(R.x))) * E.x;
        float ny = (R.y > 15.f ? R.y : __logf(1.f + __expf(R.y))) * E.y;
        float nz = (R.z > 15.f ? R.z : __logf(1.f + __expf(R.z))) * E.z;
        float nw = (R.w > 15.f ? R.w : __logf(1.f + __expf(R.w))) * E.w;
        uint4 pk;
        pk.x = bf16rne(L.x) | (bf16rne(L.y) << 16);
        pk.y = bf16rne(L.z) | (bf16rne(L.w) << 16);
        pk.z = bf16rne(nx)  | (bf16rne(ny) << 16);
        pk.w = bf16rne(nz)  | (bf16rne(nw) << 16);
        wsh[plc * WSTRIDE + k] = pk;
    }
    __syncthreads();
    const int pl = tid & 15;
    const int bh = tid >> 4;
    const int b0 = bh, b1 = bh + 16;
    const int p  = p_base + pl;
    const int od = p / (ODn * ODn);
    const int prem = p - od * (ODn * ODn);
    const int oh = prem / ODn;
    const int ow = prem - oh * ODn;
    const float4* x4 = (const float4*)x;
    const float4* s4 = (const float4*)sgn_in;
    const size_t v0 = (((size_t)b0 * Dn + od) * Dn + oh) * Dn + ow;
    const size_t v1 = (((size_t)b1 * Dn + od) * Dn + oh) * Dn + ow;
    const uint4* wp = wsh + pl * WSTRIDE;
    float a00=0.f,a01=0.f,a02=0.f,a03=0.f, a10=0.f,a11=0.f,a12=0.f,a13=0.f;
    float n00=0.f,n01=0.f,n02=0.f,n03=0.f, n10=0.f,n11=0.f,n12=0.f,n13=0.f;
#define CHAN(c, xa_c, sa_c, xb_c, sb_c)                                      \
    {                                                                        \
        const uint4 wv = wp[(c) * Tt + t];                                   \
        const float m0 = bflo(wv.x), m1 = bfhi(wv.x);                        \
        const float m2 = bflo(wv.y), m3 = bfhi(wv.y);                        \
        const float q0 = bflo(wv.z), q1 = bfhi(wv.z);                        \
        const float q2 = bflo(wv.w), q3 = bfhi(wv.w);                        \
        a00 = fmaf(xa_c, m0, a00); a01 = fmaf(xa_c, m1, a01);                \
        a02 = fmaf(xa_c, m2, a02); a03 = fmaf(xa_c, m3, a03);                \
        a10 = fmaf(xb_c, m0, a10); a11 = fmaf(xb_c, m1, a11);                \
        a12 = fmaf(xb_c, m2, a12); a13 = fmaf(xb_c, m3, a13);                \
        const float ya = (xa_c) * (sa_c);                                    \
        const float yb = (xb_c) * (sb_c);                                    \
        n00 = fmaf(ya, q0, n00); n01 = fmaf(ya, q1, n01);                    \
        n02 = fmaf(ya, q2, n02); n03 = fmaf(ya, q3, n03);                    \
        n10 = fmaf(yb, q0, n10); n11 = fmaf(yb, q1, n11);                    \
        n12 = fmaf(yb, q2, n12); n13 = fmaf(yb, q3, n13);                    \
    }
    #pragma unroll
    for (int kd = 0; kd < 3; ++kd)
        #pragma unroll
        for (int kh = 0; kh < 3; ++kh) {
            const int roff = (kd * Dn + kh) * Dn;
            #pragma unroll
            for (int kw = 0; kw < 3; ++kw) {
                const int t = (kd * 3 + kh) * 3 + kw;
                const float4 xa = x4[v0 + roff + kw];
                const float4 sa = s4[v0 + roff + kw];
                const float4 xb = x4[v1 + roff + kw];
                const float4 sb = s4[v1 + roff + kw];
                CHAN(0, xa.x, sa.x, xb.x, sb.x);
                CHAN(1, xa.y, sa.y, xb.y, sb.y);
                CHAN(2, xa.z, sa.z, xb.z, sb.z);
                CHAN(3, xa.w, sa.w, xb.w, sb.w);
            }
        }
#undef CHAN
    const float4 bi = *(const float4*)bias;
    const size_t ob0 = (size_t)b0 * Pn + p;
    const size_t ob1 = (size_t)b1 * Pn + p;
    const float4 so0 = ((const float4*)sgn_out)[ob0];
    const float4 so1 = ((const float4*)sgn_out)[ob1];
    float4 o0, o1;
    o0.x = fmaf(so0.x, n00, a00) + bi.x;
    o0.y = fmaf(so0.y, n01, a01) + bi.y;
    o0.z = fmaf(so0.z, n02, a02) + bi.z;
    o0.w = fmaf(so0.w, n03, a03) + bi.w;
    o1.x = fmaf(so1.x, n10, a10) + bi.x;
    o1.y = fmaf(so1.y, n11, a11) + bi.y;
    o1.z = fmaf(so1.z, n12, a12) + bi.z;
    o1.w = fmaf(so1.w, n13, a13) + bi.w;
    ((float4*)out)[ob0] = o0;
    ((float4*)out)[ob1] = o1;
}

extern "C" void kernel_launch(void* const* d_in, const int* in_sizes, int n_in,
                              void* d_out, int out_size, void* d_ws, size_t ws_size,
                              hipStream_t stream) {
    const float* x    = (const float*)d_in[0];
    const float* loc  = (const float*)d_in[1];
    const float* rho  = (const float*)d_in[2];
    const float* bias = (const float*)d_in[3];
    const float* eps  = (const float*)d_in[4];
    const float* si   = (const float*)d_in[5];
    const float* so   = (const float*)d_in[6];
    float* out = (float*)d_out;

    if (ws_size >= WS_NEED) {
        uint4* w = (uint4*)d_ws;
        lc3d_pack<<<dim3(NPT, 4), dim3(256), 0, stream>>>(
            (const float4*)loc, (const float4*)rho, (const float4*)eps, w);
        lc3d_main<<<dim3(NPT, 4), dim3(256), 0, stream>>>(
            w, (const float4*)x, (const float4*)si, bias,
            (const float4*)so, (float4*)out);
    } else {
        lc3d_flipout_kernel<<<dim3(Pn / PPB), dim3(256), 0, stream>>>(
            x, loc, rho, bias, eps, si, so, out);
    }
}